// Round 3
// baseline (531.770 us; speedup 1.0000x reference)
//
#include <hip/hip_runtime.h>
#include <math.h>

#define N 4096
#define D 256
#define NPOS 32768
#define TEMP 0.07f
#define INVT (1.0f / 0.07f)
#define BIGF 3.0e38f

#define BM 64        // tile rows/cols
#define NT (N / BM)  // 64 tile-blocks per dim

// workspace layout (floats):
// [0 .. NT*N)          pmin[c][r]  per-(col-tile, row) local min
// [NT*N .. 2*NT*N)     psum[c][r]  per-(col-tile, row) min-scaled expsum
// [2*NT*N .. +N)       t[r] = TEMP*log(expsum_r) - dmin_r
// [2*NT*N + N]         loss accumulator
#define WS_PMIN 0
#define WS_PSUM (NT * N)
#define WS_T    (2 * NT * N)
#define WS_ACC  (2 * NT * N + N)

__global__ void init_acc_k(float* ws) {
    if (threadIdx.x == 0 && blockIdx.x == 0) ws[WS_ACC] = 0.0f;
}

// 64x64 tile, upper triangle. 256 threads, 4x4 micro-tile.
// Fragments read straight from global (L1/L2-resident; 2KB hot set per
// 4k-step, 16-lane broadcast). No LDS in the inner loop.
__global__ __launch_bounds__(256)
void dist_tile_k(const float* __restrict__ x,
                 float* __restrict__ pmin, float* __restrict__ psum) {
    const int bm = blockIdx.x;
    const int bn = blockIdx.y;
    if (bn < bm) return;  // d symmetric: upper triangle only
    const bool diag = (bm == bn);

    const int tid = threadIdx.x;
    const int tx = tid & 15;
    const int ty = tid >> 4;

    const int rowA = bm * BM + ty * 4;
    const int rowB = bn * BM + tx * 4;

    const float4* a0 = (const float4*)(x + (size_t)(rowA + 0) * D);
    const float4* a1 = (const float4*)(x + (size_t)(rowA + 1) * D);
    const float4* a2 = (const float4*)(x + (size_t)(rowA + 2) * D);
    const float4* a3 = (const float4*)(x + (size_t)(rowA + 3) * D);
    const float4* b0 = (const float4*)(x + (size_t)(rowB + 0) * D);
    const float4* b1 = (const float4*)(x + (size_t)(rowB + 1) * D);
    const float4* b2 = (const float4*)(x + (size_t)(rowB + 2) * D);
    const float4* b3 = (const float4*)(x + (size_t)(rowB + 3) * D);

    float acc[4][4];
#pragma unroll
    for (int i = 0; i < 4; ++i)
#pragma unroll
        for (int j = 0; j < 4; ++j) acc[i][j] = 0.0f;

#pragma unroll 4
    for (int k = 0; k < D / 4; ++k) {
        const float4 A0 = a0[k], A1 = a1[k], A2 = a2[k], A3 = a3[k];
        const float4 B0 = b0[k], B1 = b1[k], B2 = b2[k], B3 = b3[k];
#define MAC(i, j, Ai, Bj)                                            \
        acc[i][j] += fabsf(Ai.x - Bj.x) + fabsf(Ai.y - Bj.y) +       \
                     fabsf(Ai.z - Bj.z) + fabsf(Ai.w - Bj.w)
        MAC(0, 0, A0, B0); MAC(0, 1, A0, B1); MAC(0, 2, A0, B2); MAC(0, 3, A0, B3);
        MAC(1, 0, A1, B0); MAC(1, 1, A1, B1); MAC(1, 2, A1, B2); MAC(1, 3, A1, B3);
        MAC(2, 0, A2, B0); MAC(2, 1, A2, B1); MAC(2, 2, A2, B2); MAC(2, 3, A2, B3);
        MAC(3, 0, A3, B0); MAC(3, 1, A3, B1); MAC(3, 2, A3, B2); MAC(3, 3, A3, B3);
#undef MAC
    }

    // diagonal exclusion: poison self-distance with BIG (min skips it,
    // exp((min-BIG)/T) -> exp(-inf) = 0)
    if (diag) {
#pragma unroll
        for (int i = 0; i < 4; ++i)
#pragma unroll
            for (int j = 0; j < 4; ++j)
                if (ty * 4 + i == tx * 4 + j) acc[i][j] = BIGF;
    }

    __shared__ float red[BM][17];
    __shared__ float stat[BM];

    // ---- row stats: min then min-scaled expsum over this tile's 64 cols ----
#pragma unroll
    for (int i = 0; i < 4; ++i) {
        const float m = fminf(fminf(acc[i][0], acc[i][1]),
                              fminf(acc[i][2], acc[i][3]));
        red[ty * 4 + i][tx] = m;
    }
    __syncthreads();
    if (tid < BM) {
        float m = BIGF;
#pragma unroll
        for (int t = 0; t < 16; ++t) m = fminf(m, red[tid][t]);
        stat[tid] = m;
    }
    __syncthreads();
    float rmin_[4];
#pragma unroll
    for (int i = 0; i < 4; ++i) rmin_[i] = stat[ty * 4 + i];
#pragma unroll
    for (int i = 0; i < 4; ++i) {
        float s = 0.0f;
#pragma unroll
        for (int j = 0; j < 4; ++j) s += __expf((rmin_[i] - acc[i][j]) * INVT);
        red[ty * 4 + i][tx] = s;
    }
    __syncthreads();
    if (tid < BM) {
        float s = 0.0f;
#pragma unroll
        for (int t = 0; t < 16; ++t) s += red[tid][t];
        pmin[(size_t)bn * N + bm * BM + tid] = stat[tid];
        psum[(size_t)bn * N + bm * BM + tid] = s;
    }

    // ---- col stats (rows of B-block over A-block's cols); diag tile's
    // col stats are the transpose of its row stats -> skip ----
    if (!diag) {
        __syncthreads();  // protect red/stat reuse (uniform branch)
#pragma unroll
        for (int j = 0; j < 4; ++j) {
            const float m = fminf(fminf(acc[0][j], acc[1][j]),
                                  fminf(acc[2][j], acc[3][j]));
            red[tx * 4 + j][ty] = m;
        }
        __syncthreads();
        if (tid < BM) {
            float m = BIGF;
#pragma unroll
            for (int t = 0; t < 16; ++t) m = fminf(m, red[tid][t]);
            stat[tid] = m;
        }
        __syncthreads();
        float cmin_[4];
#pragma unroll
        for (int j = 0; j < 4; ++j) cmin_[j] = stat[tx * 4 + j];
#pragma unroll
        for (int j = 0; j < 4; ++j) {
            float s = 0.0f;
#pragma unroll
            for (int i = 0; i < 4; ++i) s += __expf((cmin_[j] - acc[i][j]) * INVT);
            red[tx * 4 + j][ty] = s;
        }
        __syncthreads();
        if (tid < BM) {
            float s = 0.0f;
#pragma unroll
            for (int t = 0; t < 16; ++t) s += red[tid][t];
            pmin[(size_t)bm * N + bn * BM + tid] = stat[tid];
            psum[(size_t)bm * N + bn * BM + tid] = s;
        }
    }
}

// Merge the 64 per-tile partials per row: global min, rescaled expsum.
__global__ __launch_bounds__(256)
void row_stats_k(const float* __restrict__ ws_pmin,
                 const float* __restrict__ ws_psum, float* __restrict__ t) {
    const int r = blockIdx.x * 256 + threadIdx.x;
    float m = BIGF;
#pragma unroll 8
    for (int c = 0; c < NT; ++c) m = fminf(m, ws_pmin[(size_t)c * N + r]);
    float s = 0.0f;
#pragma unroll 8
    for (int c = 0; c < NT; ++c)
        s += ws_psum[(size_t)c * N + r] *
             __expf((m - ws_pmin[(size_t)c * N + r]) * INVT);
    t[r] = TEMP * __logf(s) - m;
}

// 256 blocks x 4 waves; each wave handles 32 pairs sequentially.
__global__ __launch_bounds__(256)
void pair_k(const float* __restrict__ x, const int* __restrict__ row,
            const int* __restrict__ col, const float* __restrict__ t,
            float* __restrict__ acc) {
    const int lane = threadIdx.x & 63;
    const int wave = threadIdx.x >> 6;
    float wsum = 0.0f;
    for (int it = 0; it < 32; ++it) {
        const int p = blockIdx.x * 128 + wave * 32 + it;
        const int r = row[p];
        const int c = col[p];
        const float4 a = *(const float4*)&x[(size_t)r * D + lane * 4];
        const float4 b = *(const float4*)&x[(size_t)c * D + lane * 4];
        float d = fabsf(a.x - b.x) + fabsf(a.y - b.y) +
                  fabsf(a.z - b.z) + fabsf(a.w - b.w);
#pragma unroll
        for (int off = 32; off > 0; off >>= 1) d += __shfl_xor(d, off, 64);
        if (lane == 0) wsum += d + t[r];
    }
    if (lane == 0) atomicAdd(acc, wsum);
}

__global__ void finalize_k(const float* __restrict__ acc, float* __restrict__ out) {
    if (threadIdx.x == 0 && blockIdx.x == 0)
        out[0] = acc[0] * (1.0f / (float)NPOS);
}

extern "C" void kernel_launch(void* const* d_in, const int* in_sizes, int n_in,
                              void* d_out, int out_size, void* d_ws, size_t ws_size,
                              hipStream_t stream) {
    const float* x = (const float*)d_in[0];
    const int* row = (const int*)d_in[1];
    const int* col = (const int*)d_in[2];
    float* ws = (float*)d_ws;
    float* out = (float*)d_out;

    init_acc_k<<<1, 64, 0, stream>>>(ws);

    dim3 grid(NT, NT);
    dist_tile_k<<<grid, 256, 0, stream>>>(x, ws + WS_PMIN, ws + WS_PSUM);

    row_stats_k<<<N / 256, 256, 0, stream>>>(ws + WS_PMIN, ws + WS_PSUM, ws + WS_T);

    pair_k<<<NPOS / 128, 256, 0, stream>>>(x, row, col, ws + WS_T, ws + WS_ACC);

    finalize_k<<<1, 64, 0, stream>>>(ws + WS_ACC, out);
}

// Round 4
// 364.994 us; speedup vs baseline: 1.4569x; 1.4569x over previous
//
#include <hip/hip_runtime.h>
#include <math.h>

#define N 4096
#define D 256
#define NPOS 32768
#define TEMP 0.07f
#define INVT (1.0f / 0.07f)
#define BIGF 3.0e38f

#define BM 64        // tile rows/cols
#define KB 16        // k-chunk
#define NT (N / BM)  // 64 tile-blocks per dim

// workspace layout (floats):
// [0 .. NT*N)          pmin[c][r]  per-(col-tile, row) local min
// [NT*N .. 2*NT*N)     psum[c][r]  per-(col-tile, row) min-scaled expsum
// [2*NT*N .. +N)       t[r] = TEMP*log(expsum_r) - dmin_r
// [2*NT*N + N]         loss accumulator
#define WS_PMIN 0
#define WS_PSUM (NT * N)
#define WS_T    (2 * NT * N)
#define WS_ACC  (2 * NT * N + N)

__global__ void init_acc_k(float* ws) {
    if (threadIdx.x == 0 && blockIdx.x == 0) ws[WS_ACC] = 0.0f;
}

// One wave per 64x64 tile, 8x8 micro-tile per lane (split +0/+32 fragments).
// LDS staging transposed [k][m]; lane=row writes -> bank = lane%32, 2-way free.
// Fragment reads: 8 distinct b128 addrs, 8-lane broadcast -> conflict-free.
__global__ __launch_bounds__(64, 4)
void dist_tile_k(const float* __restrict__ x,
                 float* __restrict__ pmin, float* __restrict__ psum) {
    const int bm = blockIdx.x;
    const int bn = blockIdx.y;
    if (bn < bm) return;  // d symmetric: upper triangle only
    const bool diag = (bm == bn);

    const int lane = threadIdx.x;   // 0..63
    const int tx = lane & 7;        // col group
    const int ty = lane >> 3;       // row group

    __shared__ float As[KB][BM];
    __shared__ float Bs[KB][BM];

    float acc[2][2][4][4];  // [rh][ch][i][j]
#pragma unroll
    for (int rh = 0; rh < 2; ++rh)
#pragma unroll
        for (int ch = 0; ch < 2; ++ch)
#pragma unroll
            for (int i = 0; i < 4; ++i)
#pragma unroll
                for (int j = 0; j < 4; ++j) acc[rh][ch][i][j] = 0.0f;

    const int rowA0 = bm * BM;
    const int rowB0 = bn * BM;
    const float* xa = x + (size_t)(rowA0 + lane) * D;
    const float* xb = x + (size_t)(rowB0 + lane) * D;

    for (int k0 = 0; k0 < D; k0 += KB) {
        float4 va[4], vb[4];
#pragma unroll
        for (int c = 0; c < 4; ++c) va[c] = *(const float4*)(xa + k0 + 4 * c);
#pragma unroll
        for (int c = 0; c < 4; ++c) vb[c] = *(const float4*)(xb + k0 + 4 * c);
        __syncthreads();
#pragma unroll
        for (int c = 0; c < 4; ++c) {
            As[4 * c + 0][lane] = va[c].x; As[4 * c + 1][lane] = va[c].y;
            As[4 * c + 2][lane] = va[c].z; As[4 * c + 3][lane] = va[c].w;
            Bs[4 * c + 0][lane] = vb[c].x; Bs[4 * c + 1][lane] = vb[c].y;
            Bs[4 * c + 2][lane] = vb[c].z; Bs[4 * c + 3][lane] = vb[c].w;
        }
        __syncthreads();

#pragma unroll 2
        for (int k = 0; k < KB; ++k) {
            const float4 alo = *(const float4*)&As[k][ty * 4];
            const float4 ahi = *(const float4*)&As[k][32 + ty * 4];
            const float4 blo = *(const float4*)&Bs[k][tx * 4];
            const float4 bhi = *(const float4*)&Bs[k][32 + tx * 4];
            const float av[2][4] = {{alo.x, alo.y, alo.z, alo.w},
                                    {ahi.x, ahi.y, ahi.z, ahi.w}};
            const float bv[2][4] = {{blo.x, blo.y, blo.z, blo.w},
                                    {bhi.x, bhi.y, bhi.z, bhi.w}};
#pragma unroll
            for (int rh = 0; rh < 2; ++rh)
#pragma unroll
                for (int ch = 0; ch < 2; ++ch)
#pragma unroll
                    for (int i = 0; i < 4; ++i)
#pragma unroll
                        for (int j = 0; j < 4; ++j)
                            acc[rh][ch][i][j] += fabsf(av[rh][i] - bv[ch][j]);
        }
    }

    // diagonal exclusion: poison self-distance (min skips it, exp -> 0)
    if (diag) {
#pragma unroll
        for (int rh = 0; rh < 2; ++rh)
#pragma unroll
            for (int ch = 0; ch < 2; ++ch)
#pragma unroll
                for (int i = 0; i < 4; ++i)
#pragma unroll
                    for (int j = 0; j < 4; ++j)
                        if (rh * 32 + ty * 4 + i == ch * 32 + tx * 4 + j)
                            acc[rh][ch][i][j] = BIGF;
    }

    // ---- row stats: reduce over cols = my 8 cols + shfl across tx lanes ----
#pragma unroll
    for (int rh = 0; rh < 2; ++rh) {
#pragma unroll
        for (int i = 0; i < 4; ++i) {
            float m = BIGF;
#pragma unroll
            for (int ch = 0; ch < 2; ++ch)
#pragma unroll
                for (int j = 0; j < 4; ++j) m = fminf(m, acc[rh][ch][i][j]);
            m = fminf(m, __shfl_xor(m, 1, 64));
            m = fminf(m, __shfl_xor(m, 2, 64));
            m = fminf(m, __shfl_xor(m, 4, 64));
            float s = 0.0f;
#pragma unroll
            for (int ch = 0; ch < 2; ++ch)
#pragma unroll
                for (int j = 0; j < 4; ++j)
                    s += __expf((m - acc[rh][ch][i][j]) * INVT);
            s += __shfl_xor(s, 1, 64);
            s += __shfl_xor(s, 2, 64);
            s += __shfl_xor(s, 4, 64);
            if (tx == 0) {
                const size_t idx = (size_t)bn * N + rowA0 + rh * 32 + ty * 4 + i;
                pmin[idx] = m;
                psum[idx] = s;
            }
        }
    }

    // ---- col stats: reduce over rows = my 8 rows + shfl across ty lanes ----
    if (!diag) {  // diag tile's col stats duplicate its row stats
#pragma unroll
        for (int ch = 0; ch < 2; ++ch) {
#pragma unroll
            for (int j = 0; j < 4; ++j) {
                float m = BIGF;
#pragma unroll
                for (int rh = 0; rh < 2; ++rh)
#pragma unroll
                    for (int i = 0; i < 4; ++i) m = fminf(m, acc[rh][ch][i][j]);
                m = fminf(m, __shfl_xor(m, 8, 64));
                m = fminf(m, __shfl_xor(m, 16, 64));
                m = fminf(m, __shfl_xor(m, 32, 64));
                float s = 0.0f;
#pragma unroll
                for (int rh = 0; rh < 2; ++rh)
#pragma unroll
                    for (int i = 0; i < 4; ++i)
                        s += __expf((m - acc[rh][ch][i][j]) * INVT);
                s += __shfl_xor(s, 8, 64);
                s += __shfl_xor(s, 16, 64);
                s += __shfl_xor(s, 32, 64);
                if (ty == 0) {
                    const size_t idx = (size_t)bm * N + rowB0 + ch * 32 + tx * 4 + j;
                    pmin[idx] = m;
                    psum[idx] = s;
                }
            }
        }
    }
}

// Merge the 64 per-tile partials per row: global min, rescaled expsum.
__global__ __launch_bounds__(256)
void row_stats_k(const float* __restrict__ ws_pmin,
                 const float* __restrict__ ws_psum, float* __restrict__ t) {
    const int r = blockIdx.x * 256 + threadIdx.x;
    float m = BIGF;
#pragma unroll 8
    for (int c = 0; c < NT; ++c) m = fminf(m, ws_pmin[(size_t)c * N + r]);
    float s = 0.0f;
#pragma unroll 8
    for (int c = 0; c < NT; ++c)
        s += ws_psum[(size_t)c * N + r] *
             __expf((m - ws_pmin[(size_t)c * N + r]) * INVT);
    t[r] = TEMP * __logf(s) - m;
}

// 256 blocks x 4 waves; each wave handles 32 pairs sequentially.
__global__ __launch_bounds__(256)
void pair_k(const float* __restrict__ x, const int* __restrict__ row,
            const int* __restrict__ col, const float* __restrict__ t,
            float* __restrict__ acc) {
    const int lane = threadIdx.x & 63;
    const int wave = threadIdx.x >> 6;
    float wsum = 0.0f;
    for (int it = 0; it < 32; ++it) {
        const int p = blockIdx.x * 128 + wave * 32 + it;
        const int r = row[p];
        const int c = col[p];
        const float4 a = *(const float4*)&x[(size_t)r * D + lane * 4];
        const float4 b = *(const float4*)&x[(size_t)c * D + lane * 4];
        float d = fabsf(a.x - b.x) + fabsf(a.y - b.y) +
                  fabsf(a.z - b.z) + fabsf(a.w - b.w);
#pragma unroll
        for (int off = 32; off > 0; off >>= 1) d += __shfl_xor(d, off, 64);
        if (lane == 0) wsum += d + t[r];
    }
    if (lane == 0) atomicAdd(acc, wsum);
}

__global__ void finalize_k(const float* __restrict__ acc, float* __restrict__ out) {
    if (threadIdx.x == 0 && blockIdx.x == 0)
        out[0] = acc[0] * (1.0f / (float)NPOS);
}

extern "C" void kernel_launch(void* const* d_in, const int* in_sizes, int n_in,
                              void* d_out, int out_size, void* d_ws, size_t ws_size,
                              hipStream_t stream) {
    const float* x = (const float*)d_in[0];
    const int* row = (const int*)d_in[1];
    const int* col = (const int*)d_in[2];
    float* ws = (float*)d_ws;
    float* out = (float*)d_out;

    init_acc_k<<<1, 64, 0, stream>>>(ws);

    dim3 grid(NT, NT);
    dist_tile_k<<<grid, 64, 0, stream>>>(x, ws + WS_PMIN, ws + WS_PSUM);

    row_stats_k<<<N / 256, 256, 0, stream>>>(ws + WS_PMIN, ws + WS_PSUM, ws + WS_T);

    pair_k<<<NPOS / 128, 256, 0, stream>>>(x, row, col, ws + WS_T, ws + WS_ACC);

    finalize_k<<<1, 64, 0, stream>>>(ws + WS_ACC, out);
}